// Round 3
// baseline (284.282 us; speedup 1.0000x reference)
//
#include <hip/hip_runtime.h>
#include <math.h>

#define RED_BLOCKS 256
#define NXCD 8
#define ORD_OFF 0x007fffffu  // f2ord_raw(-inf); shifted encoding makes 0 == "empty/-inf"

// Monotone order-preserving float->uint mapping, shifted so that 0 means -inf.
// (finite floats map to >= 1, so 0 unambiguously marks "no message")
__device__ __forceinline__ unsigned f2ord(float f) {
    unsigned u = __float_as_uint(f);
    u = (u & 0x80000000u) ? ~u : (u | 0x80000000u);
    return u - ORD_OFF;
}
__device__ __forceinline__ float ord2f(unsigned uo) {
    unsigned u = uo + ORD_OFF;
    unsigned v = (u & 0x80000000u) ? (u & 0x7fffffffu) : ~u;
    return __uint_as_float(v);
}

// One 64-lane wave per row: h[row] = dot(loss[row,:200], W[:200]).
__global__ void k_h(const float* __restrict__ loss, const float* __restrict__ Ws,
                    float* __restrict__ h, int n) {
    int wave = threadIdx.x >> 6, lane = threadIdx.x & 63;
    int row = blockIdx.x * 4 + wave;
    if (row >= n) return;
    float acc = 0.0f;
    if (lane < 50) {  // 200 floats = 50 float4 (row stride 800B, 16B-aligned)
        float4 a = ((const float4*)(loss + (size_t)row * 200))[lane];
        float4 w = ((const float4*)Ws)[lane];
        acc = a.x * w.x + a.y * w.y + a.z * w.z + a.w * w.w;
    }
    #pragma unroll
    for (int off = 32; off > 0; off >>= 1) acc += __shfl_down(acc, off);
    if (lane == 0) h[row] = acc;
}

__device__ __forceinline__ void edge_update(int s, int d, const float* __restrict__ h,
                                            unsigned* __restrict__ pre,
                                            unsigned* __restrict__ suc) {
    if (s == d) return;
    unsigned hs = f2ord(h[s]);
    unsigned hd = f2ord(h[d]);
    // Workgroup-scope atomic: executes in the XCD-local L2 (L1 has no atomic
    // units). Each replica is only ever touched by waves on its own XCD, so
    // L2-level atomicity is sufficient and no line ever crosses the fabric.
    __hip_atomic_fetch_max(&pre[d], hs, __ATOMIC_RELAXED, __HIP_MEMORY_SCOPE_WORKGROUP);
    __hip_atomic_fetch_max(&suc[s], hd, __ATOMIC_RELAXED, __HIP_MEMORY_SCOPE_WORKGROUP);
}

// 4 edges per thread (int4 coalesced edge loads); per-XCD private replicas.
__global__ void k_edges_xcd(const int* __restrict__ src, const int* __restrict__ dst,
                            const float* __restrict__ h, unsigned* __restrict__ preR,
                            unsigned* __restrict__ sucR, int ne, int n) {
    unsigned xcd;
    asm volatile("s_getreg_b32 %0, hwreg(HW_REG_XCC_ID)" : "=s"(xcd));
    unsigned* pre = preR + (size_t)(xcd & (NXCD - 1)) * n;
    unsigned* suc = sucR + (size_t)(xcd & (NXCD - 1)) * n;
    int t = blockIdx.x * blockDim.x + threadIdx.x;
    int base = t * 4;
    if (base + 3 < ne) {
        int4 s4 = *(const int4*)(src + base);
        int4 d4 = *(const int4*)(dst + base);
        edge_update(s4.x, d4.x, h, pre, suc);
        edge_update(s4.y, d4.y, h, pre, suc);
        edge_update(s4.z, d4.z, h, pre, suc);
        edge_update(s4.w, d4.w, h, pre, suc);
    } else {
        for (int i = base; i < ne; ++i) edge_update(src[i], dst[i], h, pre, suc);
    }
}

// Fallback (ws too small for replicas): device-scope atomics with read-filter.
__global__ void k_edges_dev(const int* __restrict__ src, const int* __restrict__ dst,
                            const float* __restrict__ h, unsigned* __restrict__ pre,
                            unsigned* __restrict__ suc, int ne) {
    int e = blockIdx.x * blockDim.x + threadIdx.x;
    if (e >= ne) return;
    int s = src[e], d = dst[e];
    if (s == d) return;
    unsigned hs = f2ord(h[s]);
    unsigned hd = f2ord(h[d]);
    if (pre[d] < hs) atomicMax(&pre[d], hs);
    if (suc[s] < hd) atomicMax(&suc[s], hd);
}

// Fold R replicas, compute logit, block-partial max (fixed RED_BLOCKS grid).
__global__ void k_logit_max(const float* __restrict__ h, const unsigned* __restrict__ preR,
                            const unsigned* __restrict__ sucR, const float* __restrict__ Wg,
                            float* __restrict__ logit, float* __restrict__ maxPart,
                            int n, int nrep) {
    __shared__ float sm[256];
    float w0 = Wg[0], w1 = Wg[1];
    float m = -INFINITY;
    for (int i = blockIdx.x * 256 + threadIdx.x; i < n; i += 256 * RED_BLOCKS) {
        unsigned p = 0, s = 0;
        for (int r = 0; r < nrep; ++r) {
            p = max(p, preR[(size_t)r * n + i]);
            s = max(s, sucR[(size_t)r * n + i]);
        }
        float pf = p ? ord2f(p) : 0.0f;  // 0 == empty -> DGL fill 0.0
        float sf = s ? ord2f(s) : 0.0f;
        float l = h[i] + w0 * pf + w1 * sf;
        logit[i] = l;
        m = fmaxf(m, l);
    }
    sm[threadIdx.x] = m;
    __syncthreads();
    for (int off = 128; off > 0; off >>= 1) {
        if (threadIdx.x < off) sm[threadIdx.x] = fmaxf(sm[threadIdx.x], sm[threadIdx.x + off]);
        __syncthreads();
    }
    if (threadIdx.x == 0) maxPart[blockIdx.x] = sm[0];
}

// Every block redundantly (deterministically) reduces the 256 max-partials, then
// writes exp(l - gmax) to out and produces block-partial sums.
__global__ void k_exp_sum(const float* __restrict__ logit, const float* __restrict__ maxPart,
                          float* __restrict__ out, float* __restrict__ sumPart, int n) {
    __shared__ float sm[256];
    sm[threadIdx.x] = maxPart[threadIdx.x];
    __syncthreads();
    for (int off = 128; off > 0; off >>= 1) {
        if (threadIdx.x < off) sm[threadIdx.x] = fmaxf(sm[threadIdx.x], sm[threadIdx.x + off]);
        __syncthreads();
    }
    float gmax = sm[0];
    __syncthreads();
    float acc = 0.0f;
    for (int i = blockIdx.x * 256 + threadIdx.x; i < n; i += 256 * RED_BLOCKS) {
        float e = expf(logit[i] - gmax);
        out[i] = e;
        acc += e;
    }
    sm[threadIdx.x] = acc;
    __syncthreads();
    for (int off = 128; off > 0; off >>= 1) {
        if (threadIdx.x < off) sm[threadIdx.x] += sm[threadIdx.x + off];
        __syncthreads();
    }
    if (threadIdx.x == 0) sumPart[blockIdx.x] = sm[0];
}

// Redundant deterministic sum-reduce of the 256 partials, then scale the output.
__global__ void k_norm(const float* __restrict__ sumPart, float* __restrict__ out, int n) {
    __shared__ float sm[256];
    sm[threadIdx.x] = sumPart[threadIdx.x];
    __syncthreads();
    for (int off = 128; off > 0; off >>= 1) {
        if (threadIdx.x < off) sm[threadIdx.x] += sm[threadIdx.x + off];
        __syncthreads();
    }
    float inv = 1.0f / sm[0];
    for (int i = blockIdx.x * 256 + threadIdx.x; i < n; i += 256 * RED_BLOCKS) out[i] *= inv;
}

extern "C" void kernel_launch(void* const* d_in, const int* in_sizes, int n_in,
                              void* d_out, int out_size, void* d_ws, size_t ws_size,
                              hipStream_t stream) {
    const float* loss = (const float*)d_in[0];   // [N, 200]
    const float* Ws   = (const float*)d_in[1];   // [1, 200]
    const float* Wg   = (const float*)d_in[2];   // [1, 2]
    const int* esrc   = (const int*)d_in[3];     // [E]
    const int* edst   = (const int*)d_in[4];     // [E]
    float* out = (float*)d_out;                  // [N]

    const int n  = in_sizes[0] / 200;
    const int ne = in_sizes[3];

    // Workspace layout (f32/u32 words): h | logit | maxPart | sumPart | preR | sucR
    float*    h       = (float*)d_ws;
    float*    logit   = h + n;
    float*    maxPart = logit + n;
    float*    sumPart = maxPart + RED_BLOCKS;
    unsigned* preR    = (unsigned*)(sumPart + RED_BLOCKS);

    size_t base_words = (size_t)2 * n + 2 * RED_BLOCKS;
    int nrep = ((base_words + (size_t)2 * NXCD * n) * 4 <= ws_size) ? NXCD : 1;
    unsigned* sucR = preR + (size_t)nrep * n;

    // Replicas: "empty" encodes as 0 -> plain memset.
    hipMemsetAsync(preR, 0, (size_t)2 * nrep * n * sizeof(unsigned), stream);

    k_h<<<(n + 3) / 4, 256, 0, stream>>>(loss, Ws, h, n);
    if (nrep == NXCD) {
        int nthreads = (ne + 3) / 4;
        k_edges_xcd<<<(nthreads + 255) / 256, 256, 0, stream>>>(esrc, edst, h, preR, sucR, ne, n);
    } else {
        k_edges_dev<<<(ne + 255) / 256, 256, 0, stream>>>(esrc, edst, h, preR, sucR, ne);
    }
    k_logit_max<<<RED_BLOCKS, 256, 0, stream>>>(h, preR, sucR, Wg, logit, maxPart, n, nrep);
    k_exp_sum<<<RED_BLOCKS, 256, 0, stream>>>(logit, maxPart, out, sumPart, n);
    k_norm<<<RED_BLOCKS, 256, 0, stream>>>(sumPart, out, n);
}

// Round 4
// 113.625 us; speedup vs baseline: 2.5019x; 2.5019x over previous
//
#include <hip/hip_runtime.h>
#include <math.h>

#define RED_BLOCKS 256
#define SB 256            // count/scatter blocks
#define CSH 9             // 512 nodes per chunk
#define CHUNK (1 << CSH)
#define ORD_OFF 0x007fffffu  // f2ord_raw(-inf); shifted so 0 == "empty/-inf"

// Monotone order-preserving float->uint mapping, shifted so 0 means -inf.
__device__ __forceinline__ unsigned f2ord(float f) {
    unsigned u = __float_as_uint(f);
    u = (u & 0x80000000u) ? ~u : (u | 0x80000000u);
    return u - ORD_OFF;
}
__device__ __forceinline__ float ord2f(unsigned uo) {
    unsigned u = uo + ORD_OFF;
    unsigned v = (u & 0x80000000u) ? (u & 0x7fffffffu) : ~u;
    return __uint_as_float(v);
}

// Identical edge-slice iteration for k_count and k_scatter (must match exactly).
template <class F>
__device__ __forceinline__ void for_each_edge(const int* __restrict__ src,
                                              const int* __restrict__ dst,
                                              int s0, int s1, F f) {
    for (int i = s0 + threadIdx.x * 4; i < s1; i += blockDim.x * 4) {
        if (i + 3 < s1) {
            int4 a = *(const int4*)(src + i);
            int4 b = *(const int4*)(dst + i);
            f(a.x, b.x); f(a.y, b.y); f(a.z, b.z); f(a.w, b.w);
        } else {
            for (int j = i; j < s1 && j < i + 4; ++j) f(src[j], dst[j]);
        }
    }
}

// One 64-lane wave per row: h[row] = dot(loss[row,:200], W[:200]).
__global__ void k_h(const float* __restrict__ loss, const float* __restrict__ Ws,
                    float* __restrict__ h, int n) {
    int wave = threadIdx.x >> 6, lane = threadIdx.x & 63;
    int row = blockIdx.x * 4 + wave;
    if (row >= n) return;
    float acc = 0.0f;
    if (lane < 50) {
        float4 a = ((const float4*)(loss + (size_t)row * 200))[lane];
        float4 w = ((const float4*)Ws)[lane];
        acc = a.x * w.x + a.y * w.y + a.z * w.z + a.w * w.w;
    }
    #pragma unroll
    for (int off = 32; off > 0; off >>= 1) acc += __shfl_down(acc, off);
    if (lane == 0) h[row] = acc;
}

// Per-block LDS histogram over 2C cols (col = dir*C + chunk); counts[block][col].
__global__ void k_count(const int* __restrict__ src, const int* __restrict__ dst,
                        unsigned* __restrict__ counts, int ne, int C, int epb) {
    extern __shared__ unsigned sh[];  // 2C words
    int ncol = 2 * C;
    for (int t = threadIdx.x; t < ncol; t += blockDim.x) sh[t] = 0;
    __syncthreads();
    int s0 = blockIdx.x * epb, s1 = min(s0 + epb, ne);
    for_each_edge(src, dst, s0, s1, [&](int s, int d) {
        if (s != d) {
            atomicAdd(&sh[d >> CSH], 1u);
            atomicAdd(&sh[C + (s >> CSH)], 1u);
        }
    });
    __syncthreads();
    for (int t = threadIdx.x; t < ncol; t += blockDim.x)
        counts[(size_t)blockIdx.x * ncol + t] = sh[t];
}

// Per-column exclusive scan over SB blocks; in-place offsets + colTotal.
__global__ void k_scanA(unsigned* __restrict__ counts, unsigned* __restrict__ colTotal, int C) {
    __shared__ unsigned sm[SB];
    int ncol = 2 * C, col = blockIdx.x, b = threadIdx.x;
    unsigned v = counts[(size_t)b * ncol + col];
    sm[b] = v;
    __syncthreads();
    // Hillis-Steele inclusive scan over SB=256
    for (int off = 1; off < SB; off <<= 1) {
        unsigned u = (b >= off) ? sm[b - off] : 0u;
        __syncthreads();
        sm[b] += u;
        __syncthreads();
    }
    counts[(size_t)b * ncol + col] = sm[b] - v;  // exclusive
    if (b == SB - 1) colTotal[col] = sm[b];
}

// Single-WG scan of 2C column totals -> colBase (exclusive, with total appended).
__global__ void k_scanB(const unsigned* __restrict__ colTotal, unsigned* __restrict__ colBase, int C) {
    __shared__ unsigned sm[512];
    int ncol = 2 * C, t = threadIdx.x;
    unsigned v = (t < ncol) ? colTotal[t] : 0u;
    sm[t] = v;
    __syncthreads();
    for (int off = 1; off < 512; off <<= 1) {
        unsigned u = (t >= off) ? sm[t - off] : 0u;
        __syncthreads();
        sm[t] += u;
        __syncthreads();
    }
    if (t < ncol) colBase[t] = sm[t] - v;
    if (t == ncol - 1) colBase[ncol] = sm[t];
}

// Scatter (node, ordval) entries into chunk-grouped buckets. No global atomics.
__global__ void k_scatter(const int* __restrict__ src, const int* __restrict__ dst,
                          const float* __restrict__ h, const unsigned* __restrict__ counts,
                          const unsigned* __restrict__ colBase, uint2* __restrict__ buckets,
                          int ne, int C, int epb) {
    extern __shared__ unsigned sOff[];  // 2C cursors
    int ncol = 2 * C;
    for (int t = threadIdx.x; t < ncol; t += blockDim.x)
        sOff[t] = colBase[t] + counts[(size_t)blockIdx.x * ncol + t];
    __syncthreads();
    int s0 = blockIdx.x * epb, s1 = min(s0 + epb, ne);
    for_each_edge(src, dst, s0, s1, [&](int s, int d) {
        if (s != d) {
            unsigned hs = f2ord(h[s]);
            unsigned hd = f2ord(h[d]);
            unsigned p0 = atomicAdd(&sOff[d >> CSH], 1u);
            buckets[p0] = make_uint2((unsigned)d, hs);
            unsigned p1 = atomicAdd(&sOff[C + (s >> CSH)], 1u);
            buckets[p1] = make_uint2((unsigned)s, hd);
        }
    });
}

// One WG per (dir,chunk): stream bucket, LDS max, write pre/suc slice.
__global__ void k_reduce(const uint2* __restrict__ buckets, const unsigned* __restrict__ colBase,
                         unsigned* __restrict__ pre, unsigned* __restrict__ suc, int n, int C) {
    __shared__ unsigned lds[CHUNK];
    int col = blockIdx.x;
    for (int t = threadIdx.x; t < CHUNK; t += blockDim.x) lds[t] = 0u;
    __syncthreads();
    unsigned lo = colBase[col], hi = colBase[col + 1];
    for (unsigned i = lo + threadIdx.x; i < hi; i += blockDim.x) {
        uint2 e = buckets[i];
        atomicMax(&lds[e.x & (CHUNK - 1)], e.y);
    }
    __syncthreads();
    int chunk = (col < C) ? col : col - C;
    unsigned* outArr = (col < C) ? pre : suc;
    for (int t = threadIdx.x; t < CHUNK; t += blockDim.x) {
        int node = (chunk << CSH) + t;
        if (node < n) outArr[node] = lds[t];
    }
}

// Fallback (ws too small): device-scope atomics with read-filter.
__global__ void k_edges_dev(const int* __restrict__ src, const int* __restrict__ dst,
                            const float* __restrict__ h, unsigned* __restrict__ pre,
                            unsigned* __restrict__ suc, int ne) {
    int e = blockIdx.x * blockDim.x + threadIdx.x;
    if (e >= ne) return;
    int s = src[e], d = dst[e];
    if (s == d) return;
    unsigned hs = f2ord(h[s]);
    unsigned hd = f2ord(h[d]);
    if (pre[d] < hs) atomicMax(&pre[d], hs);
    if (suc[s] < hd) atomicMax(&suc[s], hd);
}

// logit = h + w0*pre + w1*suc (0 == empty -> DGL fill 0.0), block-partial max.
__global__ void k_logit_max(const float* __restrict__ h, const unsigned* __restrict__ pre,
                            const unsigned* __restrict__ suc, const float* __restrict__ Wg,
                            float* __restrict__ logit, float* __restrict__ maxPart, int n) {
    __shared__ float sm[256];
    float w0 = Wg[0], w1 = Wg[1];
    float m = -INFINITY;
    for (int i = blockIdx.x * 256 + threadIdx.x; i < n; i += 256 * RED_BLOCKS) {
        unsigned p = pre[i], s = suc[i];
        float pf = p ? ord2f(p) : 0.0f;
        float sf = s ? ord2f(s) : 0.0f;
        float l = h[i] + w0 * pf + w1 * sf;
        logit[i] = l;
        m = fmaxf(m, l);
    }
    sm[threadIdx.x] = m;
    __syncthreads();
    for (int off = 128; off > 0; off >>= 1) {
        if (threadIdx.x < off) sm[threadIdx.x] = fmaxf(sm[threadIdx.x], sm[threadIdx.x + off]);
        __syncthreads();
    }
    if (threadIdx.x == 0) maxPart[blockIdx.x] = sm[0];
}

__global__ void k_exp_sum(const float* __restrict__ logit, const float* __restrict__ maxPart,
                          float* __restrict__ out, float* __restrict__ sumPart, int n) {
    __shared__ float sm[256];
    sm[threadIdx.x] = maxPart[threadIdx.x];
    __syncthreads();
    for (int off = 128; off > 0; off >>= 1) {
        if (threadIdx.x < off) sm[threadIdx.x] = fmaxf(sm[threadIdx.x], sm[threadIdx.x + off]);
        __syncthreads();
    }
    float gmax = sm[0];
    __syncthreads();
    float acc = 0.0f;
    for (int i = blockIdx.x * 256 + threadIdx.x; i < n; i += 256 * RED_BLOCKS) {
        float e = expf(logit[i] - gmax);
        out[i] = e;
        acc += e;
    }
    sm[threadIdx.x] = acc;
    __syncthreads();
    for (int off = 128; off > 0; off >>= 1) {
        if (threadIdx.x < off) sm[threadIdx.x] += sm[threadIdx.x + off];
        __syncthreads();
    }
    if (threadIdx.x == 0) sumPart[blockIdx.x] = sm[0];
}

__global__ void k_norm(const float* __restrict__ sumPart, float* __restrict__ out, int n) {
    __shared__ float sm[256];
    sm[threadIdx.x] = sumPart[threadIdx.x];
    __syncthreads();
    for (int off = 128; off > 0; off >>= 1) {
        if (threadIdx.x < off) sm[threadIdx.x] += sm[threadIdx.x + off];
        __syncthreads();
    }
    float inv = 1.0f / sm[0];
    for (int i = blockIdx.x * 256 + threadIdx.x; i < n; i += 256 * RED_BLOCKS) out[i] *= inv;
}

extern "C" void kernel_launch(void* const* d_in, const int* in_sizes, int n_in,
                              void* d_out, int out_size, void* d_ws, size_t ws_size,
                              hipStream_t stream) {
    const float* loss = (const float*)d_in[0];   // [N, 200]
    const float* Ws   = (const float*)d_in[1];   // [1, 200]
    const float* Wg   = (const float*)d_in[2];   // [1, 2]
    const int* esrc   = (const int*)d_in[3];     // [E]
    const int* edst   = (const int*)d_in[4];     // [E]
    float* out = (float*)d_out;                  // [N]

    const int n  = in_sizes[0] / 200;
    const int ne = in_sizes[3];
    const int C  = (n + CHUNK - 1) >> CSH;       // chunks per direction
    const int ncol = 2 * C;
    const int epb = (((ne + SB - 1) / SB) + 3) & ~3;  // edges per block, x4 aligned

    // ws layout (32-bit words):
    // h[n] | logit[n] | pre[n] | suc[n] | maxPart | sumPart | counts[SB*2C] |
    // colTotal[2C] | colBase[2C+1] | (pad to 16B) | buckets[2*ne] (uint2)
    float*    h        = (float*)d_ws;
    float*    logit    = h + n;
    unsigned* pre      = (unsigned*)(logit + n);
    unsigned* suc      = pre + n;
    float*    maxPart  = (float*)(suc + n);
    float*    sumPart  = maxPart + RED_BLOCKS;
    unsigned* counts   = (unsigned*)(sumPart + RED_BLOCKS);
    unsigned* colTotal = counts + (size_t)SB * ncol;
    unsigned* colBase  = colTotal + ncol;
    size_t word_off = (size_t)4 * n + 2 * RED_BLOCKS + (size_t)SB * ncol + ncol + (ncol + 1);
    word_off = (word_off + 3) & ~(size_t)3;
    uint2* buckets = (uint2*)((unsigned*)d_ws + word_off);
    size_t need_bytes = (word_off + (size_t)4 * ne) * 4;

    k_h<<<(n + 3) / 4, 256, 0, stream>>>(loss, Ws, h, n);

    if (need_bytes <= ws_size && ncol + 1 <= 512) {
        k_count<<<SB, 256, ncol * 4, stream>>>(esrc, edst, counts, ne, C, epb);
        k_scanA<<<ncol, SB, 0, stream>>>(counts, colTotal, C);
        k_scanB<<<1, 512, 0, stream>>>(colTotal, colBase, C);
        k_scatter<<<SB, 256, ncol * 4, stream>>>(esrc, edst, h, counts, colBase, buckets, ne, C, epb);
        k_reduce<<<ncol, 256, 0, stream>>>(buckets, colBase, pre, suc, n, C);
    } else {
        hipMemsetAsync(pre, 0, (size_t)2 * n * sizeof(unsigned), stream);
        k_edges_dev<<<(ne + 255) / 256, 256, 0, stream>>>(esrc, edst, h, pre, suc, ne);
    }

    k_logit_max<<<RED_BLOCKS, 256, 0, stream>>>(h, pre, suc, Wg, logit, maxPart, n);
    k_exp_sum<<<RED_BLOCKS, 256, 0, stream>>>(logit, maxPart, out, sumPart, n);
    k_norm<<<RED_BLOCKS, 256, 0, stream>>>(sumPart, out, n);
}

// Round 5
// 111.313 us; speedup vs baseline: 2.5539x; 1.0208x over previous
//
#include <hip/hip_runtime.h>
#include <math.h>

#define RED_BLOCKS 256
#define SB 1024           // count/scatter blocks (also scanA block size)
#define NT 256            // count/scatter threads per block
#define CSH 9             // 512 nodes per chunk
#define CHUNK (1 << CSH)
#define KS 4              // reduce sub-blocks per column
#define NSUB 4            // per-wave sub-histograms in k_count
#define ORD_OFF 0x007fffffu  // f2ord_raw(-inf); shifted so 0 == "-inf"

// Monotone order-preserving float->uint mapping, shifted so 0 means -inf.
__device__ __forceinline__ unsigned f2ord(float f) {
    unsigned u = __float_as_uint(f);
    u = (u & 0x80000000u) ? ~u : (u | 0x80000000u);
    return u - ORD_OFF;
}
__device__ __forceinline__ float ord2f(unsigned uo) {
    unsigned u = uo + ORD_OFF;
    unsigned v = (u & 0x80000000u) ? (u & 0x7fffffffu) : ~u;
    return __uint_as_float(v);
}

// 4B bucket entry: (quantized ord, 23b, >=1) << 9 | (node & 511).
// atomicMax on the packed word == max on value (node bits constant per slot);
// packed==0 <=> slot never touched. Quantization: drop 9 LSBs of the monotone
// code (+1 bias), midpoint reconstruct -> |rel err| <= 2^-15: far inside the
// output threshold.
__device__ __forceinline__ unsigned pack_entry(unsigned ord, int node) {
    unsigned q = (ord >> CSH) + 1;                 // fits 23 bits
    return (q << CSH) | (unsigned)(node & (CHUNK - 1));
}
__device__ __forceinline__ float unpack_val(unsigned packed) {  // packed != 0
    unsigned q = packed >> CSH;
    unsigned ordm = ((q - 1) << CSH) | (1u << (CSH - 1));
    return ord2f(ordm);
}

// Identical edge-slice iteration for k_count and k_scatter (must match exactly).
template <class F>
__device__ __forceinline__ void for_each_edge(const int* __restrict__ src,
                                              const int* __restrict__ dst,
                                              int s0, int s1, F f) {
    for (int i = s0 + threadIdx.x * 4; i < s1; i += blockDim.x * 4) {
        if (i + 3 < s1) {
            int4 a = *(const int4*)(src + i);
            int4 b = *(const int4*)(dst + i);
            f(a.x, b.x); f(a.y, b.y); f(a.z, b.z); f(a.w, b.w);
        } else {
            for (int j = i; j < s1 && j < i + 4; ++j) f(src[j], dst[j]);
        }
    }
}

// One 64-lane wave per row: h[row] = dot(loss[row,:200], W[:200]).
__global__ void k_h(const float* __restrict__ loss, const float* __restrict__ Ws,
                    float* __restrict__ h, int n) {
    int wave = threadIdx.x >> 6, lane = threadIdx.x & 63;
    int row = blockIdx.x * 4 + wave;
    if (row >= n) return;
    float acc = 0.0f;
    if (lane < 50) {
        float4 a = ((const float4*)(loss + (size_t)row * 200))[lane];
        float4 w = ((const float4*)Ws)[lane];
        acc = a.x * w.x + a.y * w.y + a.z * w.z + a.w * w.w;
    }
    #pragma unroll
    for (int off = 32; off > 0; off >>= 1) acc += __shfl_down(acc, off);
    if (lane == 0) h[row] = acc;
}

// Per-block histogram over 2C cols, NSUB per-wave sub-histograms to cut LDS
// atomic contention; counts[block][col].
__global__ void k_count(const int* __restrict__ src, const int* __restrict__ dst,
                        unsigned* __restrict__ counts, int ne, int C, int epb) {
    extern __shared__ unsigned sh[];  // NSUB * ncol
    int ncol = 2 * C;
    unsigned* my = sh + (threadIdx.x >> 6) * ncol;
    for (int t = threadIdx.x; t < NSUB * ncol; t += blockDim.x) sh[t] = 0;
    __syncthreads();
    int s0 = blockIdx.x * epb, s1 = min(s0 + epb, ne);
    for_each_edge(src, dst, s0, s1, [&](int s, int d) {
        if (s != d) {
            atomicAdd(&my[d >> CSH], 1u);
            atomicAdd(&my[C + (s >> CSH)], 1u);
        }
    });
    __syncthreads();
    for (int t = threadIdx.x; t < ncol; t += blockDim.x) {
        unsigned v = 0;
        #pragma unroll
        for (int w = 0; w < NSUB; ++w) v += sh[w * ncol + t];
        counts[(size_t)blockIdx.x * ncol + t] = v;
    }
}

// Per-column exclusive scan over SB blocks (blockDim == SB).
__global__ void k_scanA(unsigned* __restrict__ counts, unsigned* __restrict__ colTotal, int ncol) {
    __shared__ unsigned sm[SB];
    int col = blockIdx.x, b = threadIdx.x;
    unsigned v = counts[(size_t)b * ncol + col];
    sm[b] = v;
    __syncthreads();
    for (int off = 1; off < SB; off <<= 1) {
        unsigned u = (b >= off) ? sm[b - off] : 0u;
        __syncthreads();
        sm[b] += u;
        __syncthreads();
    }
    counts[(size_t)b * ncol + col] = sm[b] - v;  // exclusive
    if (b == SB - 1) colTotal[col] = sm[b];
}

// Single-WG scan of ncol column totals -> colBase (exclusive, + total appended).
__global__ void k_scanB(const unsigned* __restrict__ colTotal, unsigned* __restrict__ colBase, int ncol) {
    __shared__ unsigned sm[512];
    int t = threadIdx.x;
    unsigned v = (t < ncol) ? colTotal[t] : 0u;
    sm[t] = v;
    __syncthreads();
    for (int off = 1; off < 512; off <<= 1) {
        unsigned u = (t >= off) ? sm[t - off] : 0u;
        __syncthreads();
        sm[t] += u;
        __syncthreads();
    }
    if (t < ncol) colBase[t] = sm[t] - v;
    if (t == ncol - 1) colBase[ncol] = sm[t];
}

// Scatter packed 4B entries into chunk-grouped buckets. No global atomics.
__global__ void k_scatter(const int* __restrict__ src, const int* __restrict__ dst,
                          const float* __restrict__ h, const unsigned* __restrict__ counts,
                          const unsigned* __restrict__ colBase, unsigned* __restrict__ buckets,
                          int ne, int C, int epb) {
    extern __shared__ unsigned sOff[];  // 2C cursors
    int ncol = 2 * C;
    for (int t = threadIdx.x; t < ncol; t += blockDim.x)
        sOff[t] = colBase[t] + counts[(size_t)blockIdx.x * ncol + t];
    __syncthreads();
    int s0 = blockIdx.x * epb, s1 = min(s0 + epb, ne);
    for_each_edge(src, dst, s0, s1, [&](int s, int d) {
        if (s != d) {
            unsigned hs = f2ord(h[s]);
            unsigned hd = f2ord(h[d]);
            unsigned p0 = atomicAdd(&sOff[d >> CSH], 1u);
            buckets[p0] = pack_entry(hs, d);
            unsigned p1 = atomicAdd(&sOff[C + (s >> CSH)], 1u);
            buckets[p1] = pack_entry(hd, s);
        }
    });
}

// One WG per (col, ks): stream a quarter of the column's bucket, LDS max,
// write a 512-word partial. partials[col*KS + ks][CHUNK].
__global__ void k_reduce(const unsigned* __restrict__ buckets, const unsigned* __restrict__ colBase,
                         unsigned* __restrict__ partials) {
    __shared__ unsigned lds[CHUNK];
    int col = blockIdx.x / KS, ks = blockIdx.x - col * KS;
    for (int t = threadIdx.x; t < CHUNK; t += blockDim.x) lds[t] = 0u;
    __syncthreads();
    unsigned lo = colBase[col], hi = colBase[col + 1], len = hi - lo;
    unsigned a = lo + (unsigned)(((unsigned long long)len * ks) / KS);
    unsigned b = lo + (unsigned)(((unsigned long long)len * (ks + 1)) / KS);
    for (unsigned i = a + threadIdx.x; i < b; i += blockDim.x) {
        unsigned e = buckets[i];
        atomicMax(&lds[e & (CHUNK - 1)], e);
    }
    __syncthreads();
    unsigned* outp = partials + (size_t)blockIdx.x * CHUNK;
    for (int t = threadIdx.x; t < CHUNK; t += blockDim.x) outp[t] = lds[t];
}

// Fallback (ws too small): device-scope packed atomics into partials at ks=0.
__global__ void k_edges_dev(const int* __restrict__ src, const int* __restrict__ dst,
                            const float* __restrict__ h, unsigned* __restrict__ partials,
                            int ne, int C) {
    int e = blockIdx.x * blockDim.x + threadIdx.x;
    if (e >= ne) return;
    int s = src[e], d = dst[e];
    if (s == d) return;
    unsigned ps = pack_entry(f2ord(h[s]), d);
    unsigned pd = pack_entry(f2ord(h[d]), s);
    unsigned* slot0 = &partials[((size_t)(d >> CSH) * KS) * CHUNK + (d & (CHUNK - 1))];
    unsigned* slot1 = &partials[((size_t)(C + (s >> CSH)) * KS) * CHUNK + (s & (CHUNK - 1))];
    if (*slot0 < ps) atomicMax(slot0, ps);
    if (*slot1 < pd) atomicMax(slot1, pd);
}

// Fold KS x 2 partials, logit = h + w0*pre + w1*suc (0 == empty -> 0.0 fill),
// block-partial max (fixed RED_BLOCKS grid).
__global__ void k_logit_max(const float* __restrict__ h, const unsigned* __restrict__ partials,
                            const float* __restrict__ Wg, float* __restrict__ logit,
                            float* __restrict__ maxPart, int n, int C) {
    __shared__ float sm[256];
    float w0 = Wg[0], w1 = Wg[1];
    float m = -INFINITY;
    for (int i = blockIdx.x * 256 + threadIdx.x; i < n; i += 256 * RED_BLOCKS) {
        int chunk = i >> CSH, off = i & (CHUNK - 1);
        size_t b0 = ((size_t)chunk * KS) * CHUNK + off;
        size_t b1 = ((size_t)(C + chunk) * KS) * CHUNK + off;
        unsigned p = 0, s = 0;
        #pragma unroll
        for (int k = 0; k < KS; ++k) {
            p = max(p, partials[b0 + (size_t)k * CHUNK]);
            s = max(s, partials[b1 + (size_t)k * CHUNK]);
        }
        float pf = p ? unpack_val(p) : 0.0f;
        float sf = s ? unpack_val(s) : 0.0f;
        float l = h[i] + w0 * pf + w1 * sf;
        logit[i] = l;
        m = fmaxf(m, l);
    }
    sm[threadIdx.x] = m;
    __syncthreads();
    for (int off = 128; off > 0; off >>= 1) {
        if (threadIdx.x < off) sm[threadIdx.x] = fmaxf(sm[threadIdx.x], sm[threadIdx.x + off]);
        __syncthreads();
    }
    if (threadIdx.x == 0) maxPart[blockIdx.x] = sm[0];
}

__global__ void k_exp_sum(const float* __restrict__ logit, const float* __restrict__ maxPart,
                          float* __restrict__ out, float* __restrict__ sumPart, int n) {
    __shared__ float sm[256];
    sm[threadIdx.x] = maxPart[threadIdx.x];
    __syncthreads();
    for (int off = 128; off > 0; off >>= 1) {
        if (threadIdx.x < off) sm[threadIdx.x] = fmaxf(sm[threadIdx.x], sm[threadIdx.x + off]);
        __syncthreads();
    }
    float gmax = sm[0];
    __syncthreads();
    float acc = 0.0f;
    for (int i = blockIdx.x * 256 + threadIdx.x; i < n; i += 256 * RED_BLOCKS) {
        float e = expf(logit[i] - gmax);
        out[i] = e;
        acc += e;
    }
    sm[threadIdx.x] = acc;
    __syncthreads();
    for (int off = 128; off > 0; off >>= 1) {
        if (threadIdx.x < off) sm[threadIdx.x] += sm[threadIdx.x + off];
        __syncthreads();
    }
    if (threadIdx.x == 0) sumPart[blockIdx.x] = sm[0];
}

__global__ void k_norm(const float* __restrict__ sumPart, float* __restrict__ out, int n) {
    __shared__ float sm[256];
    sm[threadIdx.x] = sumPart[threadIdx.x];
    __syncthreads();
    for (int off = 128; off > 0; off >>= 1) {
        if (threadIdx.x < off) sm[threadIdx.x] += sm[threadIdx.x + off];
        __syncthreads();
    }
    float inv = 1.0f / sm[0];
    for (int i = blockIdx.x * 256 + threadIdx.x; i < n; i += 256 * RED_BLOCKS) out[i] *= inv;
}

extern "C" void kernel_launch(void* const* d_in, const int* in_sizes, int n_in,
                              void* d_out, int out_size, void* d_ws, size_t ws_size,
                              hipStream_t stream) {
    const float* loss = (const float*)d_in[0];   // [N, 200]
    const float* Ws   = (const float*)d_in[1];   // [1, 200]
    const float* Wg   = (const float*)d_in[2];   // [1, 2]
    const int* esrc   = (const int*)d_in[3];     // [E]
    const int* edst   = (const int*)d_in[4];     // [E]
    float* out = (float*)d_out;                  // [N]

    const int n  = in_sizes[0] / 200;
    const int ne = in_sizes[3];
    const int C  = (n + CHUNK - 1) >> CSH;       // chunks per direction
    const int ncol = 2 * C;
    const int epb = (((ne + SB - 1) / SB) + 3) & ~3;  // edges per block, x4 aligned

    // ws layout (32-bit words):
    // h[n] | logit[n] | maxPart | sumPart | partials[ncol*KS*CHUNK] |
    // counts[SB*ncol] | colTotal[ncol] | colBase[ncol+1] | buckets[2*ne]
    float*    h        = (float*)d_ws;
    float*    logit    = h + n;
    float*    maxPart  = logit + n;
    float*    sumPart  = maxPart + RED_BLOCKS;
    unsigned* partials = (unsigned*)(sumPart + RED_BLOCKS);
    size_t partials_words = (size_t)ncol * KS * CHUNK;
    unsigned* counts   = partials + partials_words;
    unsigned* colTotal = counts + (size_t)SB * ncol;
    unsigned* colBase  = colTotal + ncol;
    size_t word_off = (size_t)2 * n + 2 * RED_BLOCKS + partials_words +
                      (size_t)SB * ncol + ncol + (ncol + 1);
    word_off = (word_off + 3) & ~(size_t)3;
    unsigned* buckets = (unsigned*)d_ws + word_off;
    size_t need_bytes = (word_off + (size_t)2 * ne) * 4;

    k_h<<<(n + 3) / 4, 256, 0, stream>>>(loss, Ws, h, n);

    if (need_bytes <= ws_size && ncol < 512) {
        k_count<<<SB, NT, NSUB * ncol * 4, stream>>>(esrc, edst, counts, ne, C, epb);
        k_scanA<<<ncol, SB, 0, stream>>>(counts, colTotal, ncol);
        k_scanB<<<1, 512, 0, stream>>>(colTotal, colBase, ncol);
        k_scatter<<<SB, NT, ncol * 4, stream>>>(esrc, edst, h, counts, colBase, buckets, ne, C, epb);
        k_reduce<<<ncol * KS, 256, 0, stream>>>(buckets, colBase, partials);
    } else {
        hipMemsetAsync(partials, 0, partials_words * 4, stream);
        k_edges_dev<<<(ne + 255) / 256, 256, 0, stream>>>(esrc, edst, h, partials, ne, C);
    }

    k_logit_max<<<RED_BLOCKS, 256, 0, stream>>>(h, partials, Wg, logit, maxPart, n, C);
    k_exp_sum<<<RED_BLOCKS, 256, 0, stream>>>(logit, maxPart, out, sumPart, n);
    k_norm<<<RED_BLOCKS, 256, 0, stream>>>(sumPart, out, n);
}

// Round 6
// 105.220 us; speedup vs baseline: 2.7018x; 1.0579x over previous
//
#include <hip/hip_runtime.h>
#include <math.h>

#define RED_BLOCKS 256
#define SB 1024           // count/scatter blocks (also scanA block size)
#define NT 256            // count/scatter threads per block
#define NSUB 4            // per-wave sub-histograms in k_count
// Plan A: coarse bins, exact 8B entries
#define ASH 13
#define ACH (1 << ASH)    // 8192 nodes per bin
#define AKS 16            // reduce sub-blocks per column
// Plan B: fine bins, packed 4B entries (round-5 fallback)
#define BSH 9
#define BCH (1 << BSH)
#define BKS 4
#define ORD_OFF 0x007fffffu  // f2ord_raw(-inf); shifted so 0 == "-inf"

// Monotone order-preserving float->uint mapping, shifted so 0 means -inf.
__device__ __forceinline__ unsigned f2ord(float f) {
    unsigned u = __float_as_uint(f);
    u = (u & 0x80000000u) ? ~u : (u | 0x80000000u);
    return u - ORD_OFF;
}
__device__ __forceinline__ float ord2f(unsigned uo) {
    unsigned u = uo + ORD_OFF;
    unsigned v = (u & 0x80000000u) ? (u & 0x7fffffffu) : ~u;
    return __uint_as_float(v);
}

// Plan-B 4B entry: (quantized ord 23b, >=1) << 9 | (node & 511).
__device__ __forceinline__ unsigned pack_entry(unsigned ord, int node) {
    unsigned q = (ord >> BSH) + 1;
    return (q << BSH) | (unsigned)(node & (BCH - 1));
}
__device__ __forceinline__ float unpack_val(unsigned packed) {  // packed != 0
    unsigned q = packed >> BSH;
    unsigned ordm = ((q - 1) << BSH) | (1u << (BSH - 1));
    return ord2f(ordm);
}

// Identical edge-slice iteration for k_count and k_scatter* (must match exactly).
template <class F>
__device__ __forceinline__ void for_each_edge(const int* __restrict__ src,
                                              const int* __restrict__ dst,
                                              int s0, int s1, F f) {
    for (int i = s0 + threadIdx.x * 4; i < s1; i += blockDim.x * 4) {
        if (i + 3 < s1) {
            int4 a = *(const int4*)(src + i);
            int4 b = *(const int4*)(dst + i);
            f(a.x, b.x); f(a.y, b.y); f(a.z, b.z); f(a.w, b.w);
        } else {
            for (int j = i; j < s1 && j < i + 4; ++j) f(src[j], dst[j]);
        }
    }
}

// 16 threads per row, all 64 lanes load: h[row] = dot(loss[row,:200], W[:200]).
__global__ void k_h(const float* __restrict__ loss, const float* __restrict__ Ws,
                    float* __restrict__ h, int n) {
    int sub = threadIdx.x & 15, r = threadIdx.x >> 4;
    int row = blockIdx.x * 16 + r;
    if (row >= n) return;
    const float4* f4 = (const float4*)(loss + (size_t)row * 200);
    const float4* W4 = (const float4*)Ws;
    float4 a, w;
    float acc = 0.0f;
    a = f4[sub];      w = W4[sub];      acc += a.x*w.x + a.y*w.y + a.z*w.z + a.w*w.w;
    a = f4[sub + 16]; w = W4[sub + 16]; acc += a.x*w.x + a.y*w.y + a.z*w.z + a.w*w.w;
    a = f4[sub + 32]; w = W4[sub + 32]; acc += a.x*w.x + a.y*w.y + a.z*w.z + a.w*w.w;
    if (sub < 2) { a = f4[48 + sub]; w = W4[48 + sub]; acc += a.x*w.x + a.y*w.y + a.z*w.z + a.w*w.w; }
    #pragma unroll
    for (int off = 8; off > 0; off >>= 1) acc += __shfl_down(acc, off, 16);
    if (sub == 0) h[row] = acc;
}

// Per-block histogram over 2*nbin cols (col = dir*nbin + (node>>shift)).
__global__ void k_count(const int* __restrict__ src, const int* __restrict__ dst,
                        unsigned* __restrict__ counts, int ne, int nbin, int shift, int epb) {
    extern __shared__ unsigned sh[];  // NSUB * ncol
    int ncol = 2 * nbin;
    unsigned* my = sh + ((threadIdx.x >> 6) & (NSUB - 1)) * ncol;
    for (int t = threadIdx.x; t < NSUB * ncol; t += blockDim.x) sh[t] = 0;
    __syncthreads();
    int s0 = blockIdx.x * epb, s1 = min(s0 + epb, ne);
    for_each_edge(src, dst, s0, s1, [&](int s, int d) {
        if (s != d) {
            atomicAdd(&my[d >> shift], 1u);
            atomicAdd(&my[nbin + (s >> shift)], 1u);
        }
    });
    __syncthreads();
    for (int t = threadIdx.x; t < ncol; t += blockDim.x) {
        unsigned v = 0;
        #pragma unroll
        for (int w = 0; w < NSUB; ++w) v += sh[w * ncol + t];
        counts[(size_t)blockIdx.x * ncol + t] = v;
    }
}

// Per-column exclusive scan over SB blocks (blockDim == SB).
__global__ void k_scanA(unsigned* __restrict__ counts, unsigned* __restrict__ colTotal, int ncol) {
    __shared__ unsigned sm[SB];
    int col = blockIdx.x, b = threadIdx.x;
    unsigned v = counts[(size_t)b * ncol + col];
    sm[b] = v;
    __syncthreads();
    for (int off = 1; off < SB; off <<= 1) {
        unsigned u = (b >= off) ? sm[b - off] : 0u;
        __syncthreads();
        sm[b] += u;
        __syncthreads();
    }
    counts[(size_t)b * ncol + col] = sm[b] - v;  // exclusive
    if (b == SB - 1) colTotal[col] = sm[b];
}

// Single-WG scan of ncol column totals -> colBase (exclusive, + total appended).
__global__ void k_scanB(const unsigned* __restrict__ colTotal, unsigned* __restrict__ colBase, int ncol) {
    __shared__ unsigned sm[512];
    int t = threadIdx.x;
    unsigned v = (t < ncol) ? colTotal[t] : 0u;
    sm[t] = v;
    __syncthreads();
    for (int off = 1; off < 512; off <<= 1) {
        unsigned u = (t >= off) ? sm[t - off] : 0u;
        __syncthreads();
        sm[t] += u;
        __syncthreads();
    }
    if (t < ncol) colBase[t] = sm[t] - v;
    if (t == ncol - 1) colBase[ncol] = sm[t];
}

// ---- Plan A: exact uint2 entries into coarse bins ----
__global__ void k_scatterA(const int* __restrict__ src, const int* __restrict__ dst,
                           const float* __restrict__ h, const unsigned* __restrict__ counts,
                           const unsigned* __restrict__ colBase, uint2* __restrict__ buckets,
                           int ne, int nbin, int epb) {
    extern __shared__ unsigned sOff[];  // ncol cursors
    int ncol = 2 * nbin;
    for (int t = threadIdx.x; t < ncol; t += blockDim.x)
        sOff[t] = colBase[t] + counts[(size_t)blockIdx.x * ncol + t];
    __syncthreads();
    int s0 = blockIdx.x * epb, s1 = min(s0 + epb, ne);
    for_each_edge(src, dst, s0, s1, [&](int s, int d) {
        if (s != d) {
            unsigned hs = f2ord(h[s]);
            unsigned hd = f2ord(h[d]);
            unsigned p0 = atomicAdd(&sOff[d >> ASH], 1u);
            buckets[p0] = make_uint2((unsigned)d, hs);
            unsigned p1 = atomicAdd(&sOff[nbin + (s >> ASH)], 1u);
            buckets[p1] = make_uint2((unsigned)s, hd);
        }
    });
}

// One WG per (col, ks): stream a 1/AKS slice of the column, 32KB LDS max,
// write an ACH-word partial at partials[(col*AKS+ks)*ACH].
__global__ void k_reduceA(const uint2* __restrict__ buckets, const unsigned* __restrict__ colBase,
                          unsigned* __restrict__ partials) {
    __shared__ unsigned lds[ACH];
    int col = blockIdx.x / AKS, ks = blockIdx.x - col * AKS;
    for (int t = threadIdx.x; t < ACH; t += blockDim.x) lds[t] = 0u;
    __syncthreads();
    unsigned lo = colBase[col], hi = colBase[col + 1], len = hi - lo;
    unsigned a = lo + (unsigned)(((unsigned long long)len * ks) / AKS);
    unsigned b = lo + (unsigned)(((unsigned long long)len * (ks + 1)) / AKS);
    for (unsigned i = a + threadIdx.x; i < b; i += blockDim.x) {
        uint2 e = buckets[i];
        atomicMax(&lds[e.x & (ACH - 1)], e.y);
    }
    __syncthreads();
    unsigned* outp = partials + (size_t)blockIdx.x * ACH;
    for (int t = threadIdx.x; t < ACH; t += blockDim.x) outp[t] = lds[t];
}

// ---- Plan B: packed 4B entries into fine bins (round-5 path) ----
__global__ void k_scatterB(const int* __restrict__ src, const int* __restrict__ dst,
                           const float* __restrict__ h, const unsigned* __restrict__ counts,
                           const unsigned* __restrict__ colBase, unsigned* __restrict__ buckets,
                           int ne, int nbin, int epb) {
    extern __shared__ unsigned sOff[];
    int ncol = 2 * nbin;
    for (int t = threadIdx.x; t < ncol; t += blockDim.x)
        sOff[t] = colBase[t] + counts[(size_t)blockIdx.x * ncol + t];
    __syncthreads();
    int s0 = blockIdx.x * epb, s1 = min(s0 + epb, ne);
    for_each_edge(src, dst, s0, s1, [&](int s, int d) {
        if (s != d) {
            unsigned hs = f2ord(h[s]);
            unsigned hd = f2ord(h[d]);
            unsigned p0 = atomicAdd(&sOff[d >> BSH], 1u);
            buckets[p0] = pack_entry(hs, d);
            unsigned p1 = atomicAdd(&sOff[nbin + (s >> BSH)], 1u);
            buckets[p1] = pack_entry(hd, s);
        }
    });
}

__global__ void k_reduceB(const unsigned* __restrict__ buckets, const unsigned* __restrict__ colBase,
                          unsigned* __restrict__ partials) {
    __shared__ unsigned lds[BCH];
    int col = blockIdx.x / BKS, ks = blockIdx.x - col * BKS;
    for (int t = threadIdx.x; t < BCH; t += blockDim.x) lds[t] = 0u;
    __syncthreads();
    unsigned lo = colBase[col], hi = colBase[col + 1], len = hi - lo;
    unsigned a = lo + (unsigned)(((unsigned long long)len * ks) / BKS);
    unsigned b = lo + (unsigned)(((unsigned long long)len * (ks + 1)) / BKS);
    for (unsigned i = a + threadIdx.x; i < b; i += blockDim.x) {
        unsigned e = buckets[i];
        atomicMax(&lds[e & (BCH - 1)], e);
    }
    __syncthreads();
    unsigned* outp = partials + (size_t)blockIdx.x * BCH;
    for (int t = threadIdx.x; t < BCH; t += blockDim.x) outp[t] = lds[t];
}

// ---- Plan C: device-scope filtered atomics; pre=partials[0..), suc=partials+(1<<17) ----
__global__ void k_edges_dev(const int* __restrict__ src, const int* __restrict__ dst,
                            const float* __restrict__ h, unsigned* __restrict__ partials, int ne) {
    int e = blockIdx.x * blockDim.x + threadIdx.x;
    if (e >= ne) return;
    int s = src[e], d = dst[e];
    if (s == d) return;
    unsigned hs = f2ord(h[s]);
    unsigned hd = f2ord(h[d]);
    unsigned* slot0 = &partials[d];
    unsigned* slot1 = &partials[(1 << 17) + s];
    if (*slot0 < hs) atomicMax(slot0, hs);
    if (*slot1 < hd) atomicMax(slot1, hd);
}

// Fold ks x 2 partials, logit = h + w0*pre + w1*suc (0 == empty -> 0.0 fill),
// block-partial max (fixed RED_BLOCKS grid).
__global__ void k_logit_max(const float* __restrict__ h, const unsigned* __restrict__ partials,
                            const float* __restrict__ Wg, float* __restrict__ logit,
                            float* __restrict__ maxPart, int n, int nbin, int ks,
                            int shift, int packed) {
    __shared__ float sm[256];
    float w0 = Wg[0], w1 = Wg[1];
    unsigned mask = (1u << shift) - 1;
    size_t CH = (size_t)1 << shift;
    float m = -INFINITY;
    for (int i = blockIdx.x * 256 + threadIdx.x; i < n; i += 256 * RED_BLOCKS) {
        int chunk = i >> shift, off = i & mask;
        size_t b0 = ((size_t)chunk * ks) * CH + off;
        size_t b1 = ((size_t)(nbin + chunk) * ks) * CH + off;
        unsigned p = 0, s = 0;
        for (int k = 0; k < ks; ++k) {
            p = max(p, partials[b0 + (size_t)k * CH]);
            s = max(s, partials[b1 + (size_t)k * CH]);
        }
        float pf = p ? (packed ? unpack_val(p) : ord2f(p)) : 0.0f;
        float sf = s ? (packed ? unpack_val(s) : ord2f(s)) : 0.0f;
        float l = h[i] + w0 * pf + w1 * sf;
        logit[i] = l;
        m = fmaxf(m, l);
    }
    sm[threadIdx.x] = m;
    __syncthreads();
    for (int off = 128; off > 0; off >>= 1) {
        if (threadIdx.x < off) sm[threadIdx.x] = fmaxf(sm[threadIdx.x], sm[threadIdx.x + off]);
        __syncthreads();
    }
    if (threadIdx.x == 0) maxPart[blockIdx.x] = sm[0];
}

__global__ void k_exp_sum(const float* __restrict__ logit, const float* __restrict__ maxPart,
                          float* __restrict__ out, float* __restrict__ sumPart, int n) {
    __shared__ float sm[256];
    sm[threadIdx.x] = maxPart[threadIdx.x];
    __syncthreads();
    for (int off = 128; off > 0; off >>= 1) {
        if (threadIdx.x < off) sm[threadIdx.x] = fmaxf(sm[threadIdx.x], sm[threadIdx.x + off]);
        __syncthreads();
    }
    float gmax = sm[0];
    __syncthreads();
    float acc = 0.0f;
    for (int i = blockIdx.x * 256 + threadIdx.x; i < n; i += 256 * RED_BLOCKS) {
        float e = expf(logit[i] - gmax);
        out[i] = e;
        acc += e;
    }
    sm[threadIdx.x] = acc;
    __syncthreads();
    for (int off = 128; off > 0; off >>= 1) {
        if (threadIdx.x < off) sm[threadIdx.x] += sm[threadIdx.x + off];
        __syncthreads();
    }
    if (threadIdx.x == 0) sumPart[blockIdx.x] = sm[0];
}

__global__ void k_norm(const float* __restrict__ sumPart, float* __restrict__ out, int n) {
    __shared__ float sm[256];
    sm[threadIdx.x] = sumPart[threadIdx.x];
    __syncthreads();
    for (int off = 128; off > 0; off >>= 1) {
        if (threadIdx.x < off) sm[threadIdx.x] += sm[threadIdx.x + off];
        __syncthreads();
    }
    float inv = 1.0f / sm[0];
    for (int i = blockIdx.x * 256 + threadIdx.x; i < n; i += 256 * RED_BLOCKS) out[i] *= inv;
}

extern "C" void kernel_launch(void* const* d_in, const int* in_sizes, int n_in,
                              void* d_out, int out_size, void* d_ws, size_t ws_size,
                              hipStream_t stream) {
    const float* loss = (const float*)d_in[0];   // [N, 200]
    const float* Ws   = (const float*)d_in[1];   // [1, 200]
    const float* Wg   = (const float*)d_in[2];   // [1, 2]
    const int* esrc   = (const int*)d_in[3];     // [E]
    const int* edst   = (const int*)d_in[4];     // [E]
    float* out = (float*)d_out;                  // [N]

    const int n  = in_sizes[0] / 200;
    const int ne = in_sizes[3];
    const int epb = (((ne + SB - 1) / SB) + 3) & ~3;  // edges per block, x4 aligned

    // Common prefix (32-bit words): h[n] | logit[n] | maxPart | sumPart | <plan region>
    float* h       = (float*)d_ws;
    float* logit   = h + n;
    float* maxPart = logit + n;
    float* sumPart = maxPart + RED_BLOCKS;
    unsigned* planw = (unsigned*)(sumPart + RED_BLOCKS);
    size_t common = (size_t)2 * n + 2 * RED_BLOCKS;

    // Plan A geometry
    const int nbinA = (n + ACH - 1) >> ASH, ncolA = 2 * nbinA;
    size_t partA = (size_t)ncolA * AKS * ACH;
    size_t scanA_w = (size_t)SB * ncolA + ncolA + (ncolA + 1);
    size_t offA = (common + partA + scanA_w + 3) & ~(size_t)3;
    size_t needA = (offA + (size_t)4 * ne) * 4;   // uint2 buckets: <=2*ne entries
    // Plan B geometry
    const int nbinB = (n + BCH - 1) >> BSH, ncolB = 2 * nbinB;
    size_t partB = (size_t)ncolB * BKS * BCH;
    size_t scanB_w = (size_t)SB * ncolB + ncolB + (ncolB + 1);
    size_t offB = (common + partB + scanB_w + 3) & ~(size_t)3;
    size_t needB = (offB + (size_t)2 * ne) * 4;

    k_h<<<(n + 15) / 16, 256, 0, stream>>>(loss, Ws, h, n);

    if (needA <= ws_size && ncolA <= 512) {
        unsigned* partials = planw;
        unsigned* counts   = partials + partA;
        unsigned* colTotal = counts + (size_t)SB * ncolA;
        unsigned* colBase  = colTotal + ncolA;
        uint2*    buckets  = (uint2*)((unsigned*)d_ws + offA);
        k_count<<<SB, NT, NSUB * ncolA * 4, stream>>>(esrc, edst, counts, ne, nbinA, ASH, epb);
        k_scanA<<<ncolA, SB, 0, stream>>>(counts, colTotal, ncolA);
        k_scanB<<<1, 512, 0, stream>>>(colTotal, colBase, ncolA);
        k_scatterA<<<SB, NT, ncolA * 4, stream>>>(esrc, edst, h, counts, colBase, buckets, ne, nbinA, epb);
        k_reduceA<<<ncolA * AKS, 256, 0, stream>>>(buckets, colBase, partials);
        k_logit_max<<<RED_BLOCKS, 256, 0, stream>>>(h, partials, Wg, logit, maxPart, n, nbinA, AKS, ASH, 0);
    } else if (needB <= ws_size && ncolB <= 512) {
        unsigned* partials = planw;
        unsigned* counts   = partials + partB;
        unsigned* colTotal = counts + (size_t)SB * ncolB;
        unsigned* colBase  = colTotal + ncolB;
        unsigned* buckets  = (unsigned*)d_ws + offB;
        k_count<<<SB, NT, NSUB * ncolB * 4, stream>>>(esrc, edst, counts, ne, nbinB, BSH, epb);
        k_scanA<<<ncolB, SB, 0, stream>>>(counts, colTotal, ncolB);
        k_scanB<<<1, 512, 0, stream>>>(colTotal, colBase, ncolB);
        k_scatterB<<<SB, NT, ncolB * 4, stream>>>(esrc, edst, h, counts, colBase, buckets, ne, nbinB, epb);
        k_reduceB<<<ncolB * BKS, 256, 0, stream>>>(buckets, colBase, partials);
        k_logit_max<<<RED_BLOCKS, 256, 0, stream>>>(h, partials, Wg, logit, maxPart, n, nbinB, BKS, BSH, 1);
    } else {
        unsigned* partials = planw;
        hipMemsetAsync(partials, 0, (size_t)2 * (1 << 17) * 4, stream);
        k_edges_dev<<<(ne + 255) / 256, 256, 0, stream>>>(esrc, edst, h, partials, ne);
        k_logit_max<<<RED_BLOCKS, 256, 0, stream>>>(h, partials, Wg, logit, maxPart, n, 1, 1, 17, 0);
    }

    k_exp_sum<<<RED_BLOCKS, 256, 0, stream>>>(logit, maxPart, out, sumPart, n);
    k_norm<<<RED_BLOCKS, 256, 0, stream>>>(sumPart, out, n);
}

// Round 7
// 92.795 us; speedup vs baseline: 3.0635x; 1.1339x over previous
//
#include <hip/hip_runtime.h>
#include <math.h>

#define RED_BLOCKS 256
#define SB 1024           // count/scatter blocks (also scanA block size)
#define NT 256            // count/scatter threads per block
#define NSUB 4            // per-wave sub-histograms in count
#define MAXCOL 64         // plan-A max column count (2*nbinA)
// Plan A: coarse bins, exact 8B entries
#define ASH 13
#define ACH (1 << ASH)    // 8192 nodes per bin
#define AKS 16            // reduce sub-blocks per column
// Plan B: fine bins, packed 4B entries
#define BSH 9
#define BCH (1 << BSH)
#define BKS 4
#define ORD_OFF 0x007fffffu  // f2ord_raw(-inf); shifted so 0 == "-inf"

// Monotone order-preserving float->uint mapping, shifted so 0 means -inf.
__device__ __forceinline__ unsigned f2ord(float f) {
    unsigned u = __float_as_uint(f);
    u = (u & 0x80000000u) ? ~u : (u | 0x80000000u);
    return u - ORD_OFF;
}
__device__ __forceinline__ float ord2f(unsigned uo) {
    unsigned u = uo + ORD_OFF;
    unsigned v = (u & 0x80000000u) ? (u & 0x7fffffffu) : ~u;
    return __uint_as_float(v);
}

// Plan-B 4B entry: (quantized ord 23b, >=1) << 9 | (node & 511).
__device__ __forceinline__ unsigned pack_entry(unsigned ord, int node) {
    unsigned q = (ord >> BSH) + 1;
    return (q << BSH) | (unsigned)(node & (BCH - 1));
}
__device__ __forceinline__ float unpack_val(unsigned packed) {  // packed != 0
    unsigned q = packed >> BSH;
    unsigned ordm = ((q - 1) << BSH) | (1u << (BSH - 1));
    return ord2f(ordm);
}

// Identical edge-slice iteration for count and scatter (must match exactly).
template <class F>
__device__ __forceinline__ void for_each_edge(const int* __restrict__ src,
                                              const int* __restrict__ dst,
                                              int s0, int s1, F f) {
    for (int i = s0 + threadIdx.x * 4; i < s1; i += blockDim.x * 4) {
        if (i + 3 < s1) {
            int4 a = *(const int4*)(src + i);
            int4 b = *(const int4*)(dst + i);
            f(a.x, b.x); f(a.y, b.y); f(a.z, b.z); f(a.w, b.w);
        } else {
            for (int j = i; j < s1 && j < i + 4; ++j) f(src[j], dst[j]);
        }
    }
}

__device__ __forceinline__ void h_row_body(const float* __restrict__ loss,
                                           const float* __restrict__ Ws,
                                           float* __restrict__ h, int n, int blk) {
    int sub = threadIdx.x & 15, r = threadIdx.x >> 4;
    int row = blk * 16 + r;
    if (row >= n) return;
    const float4* f4 = (const float4*)(loss + (size_t)row * 200);
    const float4* W4 = (const float4*)Ws;
    float4 a, w;
    float acc = 0.0f;
    a = f4[sub];      w = W4[sub];      acc += a.x*w.x + a.y*w.y + a.z*w.z + a.w*w.w;
    a = f4[sub + 16]; w = W4[sub + 16]; acc += a.x*w.x + a.y*w.y + a.z*w.z + a.w*w.w;
    a = f4[sub + 32]; w = W4[sub + 32]; acc += a.x*w.x + a.y*w.y + a.z*w.z + a.w*w.w;
    if (sub < 2) { a = f4[48 + sub]; w = W4[48 + sub]; acc += a.x*w.x + a.y*w.y + a.z*w.z + a.w*w.w; }
    #pragma unroll
    for (int off = 8; off > 0; off >>= 1) acc += __shfl_down(acc, off, 16);
    if (sub == 0) h[row] = acc;
}

// Fused: blocks [0,Gh) compute h rows; blocks [Gh, Gh+SB) histogram the edges.
// Independent work overlapped in one launch.
__global__ void k_h_count(const float* __restrict__ loss, const float* __restrict__ Ws,
                          float* __restrict__ h, int n,
                          const int* __restrict__ src, const int* __restrict__ dst,
                          unsigned* __restrict__ counts, int ne, int nbin, int Gh, int epb) {
    __shared__ unsigned shc[NSUB * MAXCOL];
    if ((int)blockIdx.x < Gh) {
        h_row_body(loss, Ws, h, n, blockIdx.x);
        return;
    }
    int cb = blockIdx.x - Gh;
    int ncol = 2 * nbin;
    unsigned* my = shc + ((threadIdx.x >> 6) & (NSUB - 1)) * ncol;
    for (int t = threadIdx.x; t < NSUB * ncol; t += blockDim.x) shc[t] = 0;
    __syncthreads();
    int s0 = cb * epb, s1 = min(s0 + epb, ne);
    for_each_edge(src, dst, s0, s1, [&](int s, int d) {
        if (s != d) {
            atomicAdd(&my[d >> ASH], 1u);
            atomicAdd(&my[nbin + (s >> ASH)], 1u);
        }
    });
    __syncthreads();
    for (int t = threadIdx.x; t < ncol; t += blockDim.x) {
        unsigned v = 0;
        #pragma unroll
        for (int w = 0; w < NSUB; ++w) v += shc[w * ncol + t];
        counts[(size_t)cb * ncol + t] = v;
    }
}

// Standalone h (plans B/C).
__global__ void k_h(const float* __restrict__ loss, const float* __restrict__ Ws,
                    float* __restrict__ h, int n) {
    h_row_body(loss, Ws, h, n, blockIdx.x);
}

// Plan-B histogram (dynamic ncol).
__global__ void k_count(const int* __restrict__ src, const int* __restrict__ dst,
                        unsigned* __restrict__ counts, int ne, int nbin, int shift, int epb) {
    extern __shared__ unsigned sh[];
    int ncol = 2 * nbin;
    unsigned* my = sh + ((threadIdx.x >> 6) & (NSUB - 1)) * ncol;
    for (int t = threadIdx.x; t < NSUB * ncol; t += blockDim.x) sh[t] = 0;
    __syncthreads();
    int s0 = blockIdx.x * epb, s1 = min(s0 + epb, ne);
    for_each_edge(src, dst, s0, s1, [&](int s, int d) {
        if (s != d) {
            atomicAdd(&my[d >> shift], 1u);
            atomicAdd(&my[nbin + (s >> shift)], 1u);
        }
    });
    __syncthreads();
    for (int t = threadIdx.x; t < ncol; t += blockDim.x) {
        unsigned v = 0;
        #pragma unroll
        for (int w = 0; w < NSUB; ++w) v += sh[w * ncol + t];
        counts[(size_t)blockIdx.x * ncol + t] = v;
    }
}

// Per-column exclusive scan over SB blocks (blockDim == SB).
__global__ void k_scanA(unsigned* __restrict__ counts, unsigned* __restrict__ colTotal, int ncol) {
    __shared__ unsigned sm[SB];
    int col = blockIdx.x, b = threadIdx.x;
    unsigned v = counts[(size_t)b * ncol + col];
    sm[b] = v;
    __syncthreads();
    for (int off = 1; off < SB; off <<= 1) {
        unsigned u = (b >= off) ? sm[b - off] : 0u;
        __syncthreads();
        sm[b] += u;
        __syncthreads();
    }
    counts[(size_t)b * ncol + col] = sm[b] - v;  // exclusive
    if (b == SB - 1) colTotal[col] = sm[b];
}

// Plan-B only: single-WG scan of ncol totals -> colBase.
__global__ void k_scanB(const unsigned* __restrict__ colTotal, unsigned* __restrict__ colBase, int ncol) {
    __shared__ unsigned sm[512];
    int t = threadIdx.x;
    unsigned v = (t < ncol) ? colTotal[t] : 0u;
    sm[t] = v;
    __syncthreads();
    for (int off = 1; off < 512; off <<= 1) {
        unsigned u = (t >= off) ? sm[t - off] : 0u;
        __syncthreads();
        sm[t] += u;
        __syncthreads();
    }
    if (t < ncol) colBase[t] = sm[t] - v;
    if (t == ncol - 1) colBase[ncol] = sm[t];
}

// ---- Plan A: exact uint2 entries into coarse bins; colBase recomputed in-block ----
__global__ void k_scatterA(const int* __restrict__ src, const int* __restrict__ dst,
                           const float* __restrict__ h, const unsigned* __restrict__ counts,
                           const unsigned* __restrict__ colTotal, uint2* __restrict__ buckets,
                           int ne, int nbin, int epb) {
    __shared__ unsigned sBase[MAXCOL + 1];
    __shared__ unsigned sOff[MAXCOL];
    int ncol = 2 * nbin;
    if (threadIdx.x == 0) {
        unsigned acc = 0;
        for (int c = 0; c < ncol; ++c) { sBase[c] = acc; acc += colTotal[c]; }
        sBase[ncol] = acc;
    }
    __syncthreads();
    for (int t = threadIdx.x; t < ncol; t += blockDim.x)
        sOff[t] = sBase[t] + counts[(size_t)blockIdx.x * ncol + t];
    __syncthreads();
    int s0 = blockIdx.x * epb, s1 = min(s0 + epb, ne);
    for_each_edge(src, dst, s0, s1, [&](int s, int d) {
        if (s != d) {
            unsigned hs = f2ord(h[s]);
            unsigned hd = f2ord(h[d]);
            unsigned p0 = atomicAdd(&sOff[d >> ASH], 1u);
            buckets[p0] = make_uint2((unsigned)d, hs);
            unsigned p1 = atomicAdd(&sOff[nbin + (s >> ASH)], 1u);
            buckets[p1] = make_uint2((unsigned)s, hd);
        }
    });
}

// One WG per (col, ks): stream a 1/AKS slice (4 loads in flight), 32KB LDS max,
// write an ACH-word partial at partials[(col*AKS+ks)*ACH].
__global__ void k_reduceA(const uint2* __restrict__ buckets, const unsigned* __restrict__ colTotal,
                          unsigned* __restrict__ partials, int ncol) {
    __shared__ unsigned lds[ACH];
    __shared__ unsigned sBase[MAXCOL + 1];
    int col = blockIdx.x / AKS, ks = blockIdx.x - col * AKS;
    if (threadIdx.x == 0) {
        unsigned acc = 0;
        for (int c = 0; c < ncol; ++c) { sBase[c] = acc; acc += colTotal[c]; }
        sBase[ncol] = acc;
    }
    for (int t = threadIdx.x; t < ACH; t += blockDim.x) lds[t] = 0u;
    __syncthreads();
    unsigned lo = sBase[col], hi = sBase[col + 1], len = hi - lo;
    unsigned a = lo + (unsigned)(((unsigned long long)len * ks) / AKS);
    unsigned b = lo + (unsigned)(((unsigned long long)len * (ks + 1)) / AKS);
    unsigned i = a + threadIdx.x;
    for (; i + 768 < b; i += 1024) {   // 4 independent loads in flight
        uint2 e0 = buckets[i];
        uint2 e1 = buckets[i + 256];
        uint2 e2 = buckets[i + 512];
        uint2 e3 = buckets[i + 768];
        atomicMax(&lds[e0.x & (ACH - 1)], e0.y);
        atomicMax(&lds[e1.x & (ACH - 1)], e1.y);
        atomicMax(&lds[e2.x & (ACH - 1)], e2.y);
        atomicMax(&lds[e3.x & (ACH - 1)], e3.y);
    }
    for (; i < b; i += 256) {
        uint2 e = buckets[i];
        atomicMax(&lds[e.x & (ACH - 1)], e.y);
    }
    __syncthreads();
    unsigned* outp = partials + (size_t)blockIdx.x * ACH;
    for (int t = threadIdx.x; t < ACH; t += blockDim.x) outp[t] = lds[t];
}

// ---- Plan B: packed 4B entries into fine bins ----
__global__ void k_scatterB(const int* __restrict__ src, const int* __restrict__ dst,
                           const float* __restrict__ h, const unsigned* __restrict__ counts,
                           const unsigned* __restrict__ colBase, unsigned* __restrict__ buckets,
                           int ne, int nbin, int epb) {
    extern __shared__ unsigned sOff[];
    int ncol = 2 * nbin;
    for (int t = threadIdx.x; t < ncol; t += blockDim.x)
        sOff[t] = colBase[t] + counts[(size_t)blockIdx.x * ncol + t];
    __syncthreads();
    int s0 = blockIdx.x * epb, s1 = min(s0 + epb, ne);
    for_each_edge(src, dst, s0, s1, [&](int s, int d) {
        if (s != d) {
            unsigned hs = f2ord(h[s]);
            unsigned hd = f2ord(h[d]);
            unsigned p0 = atomicAdd(&sOff[d >> BSH], 1u);
            buckets[p0] = pack_entry(hs, d);
            unsigned p1 = atomicAdd(&sOff[nbin + (s >> BSH)], 1u);
            buckets[p1] = pack_entry(hd, s);
        }
    });
}

__global__ void k_reduceB(const unsigned* __restrict__ buckets, const unsigned* __restrict__ colBase,
                          unsigned* __restrict__ partials) {
    __shared__ unsigned lds[BCH];
    int col = blockIdx.x / BKS, ks = blockIdx.x - col * BKS;
    for (int t = threadIdx.x; t < BCH; t += blockDim.x) lds[t] = 0u;
    __syncthreads();
    unsigned lo = colBase[col], hi = colBase[col + 1], len = hi - lo;
    unsigned a = lo + (unsigned)(((unsigned long long)len * ks) / BKS);
    unsigned b = lo + (unsigned)(((unsigned long long)len * (ks + 1)) / BKS);
    for (unsigned i = a + threadIdx.x; i < b; i += blockDim.x) {
        unsigned e = buckets[i];
        atomicMax(&lds[e & (BCH - 1)], e);
    }
    __syncthreads();
    unsigned* outp = partials + (size_t)blockIdx.x * BCH;
    for (int t = threadIdx.x; t < BCH; t += blockDim.x) outp[t] = lds[t];
}

// ---- Plan C: device-scope filtered atomics ----
__global__ void k_edges_dev(const int* __restrict__ src, const int* __restrict__ dst,
                            const float* __restrict__ h, unsigned* __restrict__ partials, int ne) {
    int e = blockIdx.x * blockDim.x + threadIdx.x;
    if (e >= ne) return;
    int s = src[e], d = dst[e];
    if (s == d) return;
    unsigned hs = f2ord(h[s]);
    unsigned hd = f2ord(h[d]);
    unsigned* slot0 = &partials[d];
    unsigned* slot1 = &partials[(1 << 17) + s];
    if (*slot0 < hs) atomicMax(slot0, hs);
    if (*slot1 < hd) atomicMax(slot1, hd);
}

// Fold ks x 2 partials, logit = h + w0*pre + w1*suc (0 == empty -> 0.0 fill),
// block-partial max (fixed RED_BLOCKS grid).
__global__ void k_logit_max(const float* __restrict__ h, const unsigned* __restrict__ partials,
                            const float* __restrict__ Wg, float* __restrict__ logit,
                            float* __restrict__ maxPart, int n, int nbin, int ks,
                            int shift, int packed) {
    __shared__ float sm[256];
    float w0 = Wg[0], w1 = Wg[1];
    unsigned mask = (1u << shift) - 1;
    size_t CH = (size_t)1 << shift;
    float m = -INFINITY;
    for (int i = blockIdx.x * 256 + threadIdx.x; i < n; i += 256 * RED_BLOCKS) {
        int chunk = i >> shift, off = i & mask;
        size_t b0 = ((size_t)chunk * ks) * CH + off;
        size_t b1 = ((size_t)(nbin + chunk) * ks) * CH + off;
        unsigned p = 0, s = 0;
        for (int k = 0; k < ks; ++k) {
            p = max(p, partials[b0 + (size_t)k * CH]);
            s = max(s, partials[b1 + (size_t)k * CH]);
        }
        float pf = p ? (packed ? unpack_val(p) : ord2f(p)) : 0.0f;
        float sf = s ? (packed ? unpack_val(s) : ord2f(s)) : 0.0f;
        float l = h[i] + w0 * pf + w1 * sf;
        logit[i] = l;
        m = fmaxf(m, l);
    }
    sm[threadIdx.x] = m;
    __syncthreads();
    for (int off = 128; off > 0; off >>= 1) {
        if (threadIdx.x < off) sm[threadIdx.x] = fmaxf(sm[threadIdx.x], sm[threadIdx.x + off]);
        __syncthreads();
    }
    if (threadIdx.x == 0) maxPart[blockIdx.x] = sm[0];
}

__global__ void k_exp_sum(const float* __restrict__ logit, const float* __restrict__ maxPart,
                          float* __restrict__ out, float* __restrict__ sumPart, int n) {
    __shared__ float sm[256];
    sm[threadIdx.x] = maxPart[threadIdx.x];
    __syncthreads();
    for (int off = 128; off > 0; off >>= 1) {
        if (threadIdx.x < off) sm[threadIdx.x] = fmaxf(sm[threadIdx.x], sm[threadIdx.x + off]);
        __syncthreads();
    }
    float gmax = sm[0];
    __syncthreads();
    float acc = 0.0f;
    for (int i = blockIdx.x * 256 + threadIdx.x; i < n; i += 256 * RED_BLOCKS) {
        float e = expf(logit[i] - gmax);
        out[i] = e;
        acc += e;
    }
    sm[threadIdx.x] = acc;
    __syncthreads();
    for (int off = 128; off > 0; off >>= 1) {
        if (threadIdx.x < off) sm[threadIdx.x] += sm[threadIdx.x + off];
        __syncthreads();
    }
    if (threadIdx.x == 0) sumPart[blockIdx.x] = sm[0];
}

__global__ void k_norm(const float* __restrict__ sumPart, float* __restrict__ out, int n) {
    __shared__ float sm[256];
    sm[threadIdx.x] = sumPart[threadIdx.x];
    __syncthreads();
    for (int off = 128; off > 0; off >>= 1) {
        if (threadIdx.x < off) sm[threadIdx.x] += sm[threadIdx.x + off];
        __syncthreads();
    }
    float inv = 1.0f / sm[0];
    for (int i = blockIdx.x * 256 + threadIdx.x; i < n; i += 256 * RED_BLOCKS) out[i] *= inv;
}

extern "C" void kernel_launch(void* const* d_in, const int* in_sizes, int n_in,
                              void* d_out, int out_size, void* d_ws, size_t ws_size,
                              hipStream_t stream) {
    const float* loss = (const float*)d_in[0];   // [N, 200]
    const float* Ws   = (const float*)d_in[1];   // [1, 200]
    const float* Wg   = (const float*)d_in[2];   // [1, 2]
    const int* esrc   = (const int*)d_in[3];     // [E]
    const int* edst   = (const int*)d_in[4];     // [E]
    float* out = (float*)d_out;                  // [N]

    const int n  = in_sizes[0] / 200;
    const int ne = in_sizes[3];
    const int epb = (((ne + SB - 1) / SB) + 3) & ~3;  // edges per block, x4 aligned
    const int Gh  = (n + 15) / 16;

    // Common prefix (32-bit words): h[n] | logit[n] | maxPart | sumPart | <plan region>
    float* h       = (float*)d_ws;
    float* logit   = h + n;
    float* maxPart = logit + n;
    float* sumPart = maxPart + RED_BLOCKS;
    unsigned* planw = (unsigned*)(sumPart + RED_BLOCKS);
    size_t common = (size_t)2 * n + 2 * RED_BLOCKS;

    // Plan A geometry
    const int nbinA = (n + ACH - 1) >> ASH, ncolA = 2 * nbinA;
    size_t partA = (size_t)ncolA * AKS * ACH;
    size_t scanAw = (size_t)SB * ncolA + ncolA;
    size_t offA = (common + partA + scanAw + 3) & ~(size_t)3;
    size_t needA = (offA + (size_t)4 * ne) * 4;   // uint2 buckets: <=2*ne entries
    // Plan B geometry
    const int nbinB = (n + BCH - 1) >> BSH, ncolB = 2 * nbinB;
    size_t partB = (size_t)ncolB * BKS * BCH;
    size_t scanBw = (size_t)SB * ncolB + ncolB + (ncolB + 1);
    size_t offB = (common + partB + scanBw + 3) & ~(size_t)3;
    size_t needB = (offB + (size_t)2 * ne) * 4;

    if (needA <= ws_size && ncolA <= MAXCOL) {
        unsigned* partials = planw;
        unsigned* counts   = partials + partA;
        unsigned* colTotal = counts + (size_t)SB * ncolA;
        uint2*    buckets  = (uint2*)((unsigned*)d_ws + offA);
        k_h_count<<<Gh + SB, NT, 0, stream>>>(loss, Ws, h, n, esrc, edst, counts, ne, nbinA, Gh, epb);
        k_scanA<<<ncolA, SB, 0, stream>>>(counts, colTotal, ncolA);
        k_scatterA<<<SB, NT, 0, stream>>>(esrc, edst, h, counts, colTotal, buckets, ne, nbinA, epb);
        k_reduceA<<<ncolA * AKS, 256, 0, stream>>>(buckets, colTotal, partials, ncolA);
        k_logit_max<<<RED_BLOCKS, 256, 0, stream>>>(h, partials, Wg, logit, maxPart, n, nbinA, AKS, ASH, 0);
    } else if (needB <= ws_size && ncolB <= 512) {
        unsigned* partials = planw;
        unsigned* counts   = partials + partB;
        unsigned* colTotal = counts + (size_t)SB * ncolB;
        unsigned* colBase  = colTotal + ncolB;
        unsigned* buckets  = (unsigned*)d_ws + offB;
        k_h<<<Gh, 256, 0, stream>>>(loss, Ws, h, n);
        k_count<<<SB, NT, NSUB * ncolB * 4, stream>>>(esrc, edst, counts, ne, nbinB, BSH, epb);
        k_scanA<<<ncolB, SB, 0, stream>>>(counts, colTotal, ncolB);
        k_scanB<<<1, 512, 0, stream>>>(colTotal, colBase, ncolB);
        k_scatterB<<<SB, NT, ncolB * 4, stream>>>(esrc, edst, h, counts, colBase, buckets, ne, nbinB, epb);
        k_reduceB<<<ncolB * BKS, 256, 0, stream>>>(buckets, colBase, partials);
        k_logit_max<<<RED_BLOCKS, 256, 0, stream>>>(h, partials, Wg, logit, maxPart, n, nbinB, BKS, BSH, 1);
    } else {
        unsigned* partials = planw;
        k_h<<<Gh, 256, 0, stream>>>(loss, Ws, h, n);
        hipMemsetAsync(partials, 0, (size_t)2 * (1 << 17) * 4, stream);
        k_edges_dev<<<(ne + 255) / 256, 256, 0, stream>>>(esrc, edst, h, partials, ne);
        k_logit_max<<<RED_BLOCKS, 256, 0, stream>>>(h, partials, Wg, logit, maxPart, n, 1, 1, 17, 0);
    }

    k_exp_sum<<<RED_BLOCKS, 256, 0, stream>>>(logit, maxPart, out, sumPart, n);
    k_norm<<<RED_BLOCKS, 256, 0, stream>>>(sumPart, out, n);
}